// Round 15
// baseline (285.332 us; speedup 1.0000x reference)
//
#include <hip/hip_runtime.h>
#include <math.h>

// Fused Conv3d(3->16, k=3, valid) + bias + min over D + softmax over C.
// N=16, CIN=3, COUT=16, K=3, D=H=W=64 -> out [16,16,62,62] fp32.
//
// R18: R17 with the launcher memset sized in BYTES (out_size is the
// ELEMENT count per the harness's to_numpy(np.float32,(out_size,))).
// R17's nan was exactly dec_min(0)=NaN on the 3/4 of the buffer the
// short memset never pre-filled with 0xFF keys.
// Structure (unchanged): D-split for 2 blocks/CU. R16 (4px/thread, CH=4,
// VGPR=44, no spill) ran 200us at 44% occ = 1 block/CU, grid-limited.
// Min-over-D is associative: depth halves [0,35]/[28,63] (grid 512 =
// 2 blocks/CU), each block partial-mins d' [0,31]/[30,61] (overlap
// idempotent, FMA order bitwise-identical to R16), merged via monotone-
// encoded atomicMin into out (pre-filled 0xFF), then kernel2 decodes +
// bias + 16-lane-shuffle softmax in-place.
// Prediction: occ ~85%, k1 ~110-140us, total ~125-155us. If dur ~200 at
// occ 85% -> stall is the 5.5e7 bank conflicts -> swizzle next.

#define CH 4  // d-slices per staged chunk

__device__ __forceinline__ unsigned enc_min(float f) {
    unsigned u = __float_as_uint(f);
    return (u & 0x80000000u) ? ~u : (u | 0x80000000u);
}
__device__ __forceinline__ float dec_min(unsigned k) {
    unsigned u = (k & 0x80000000u) ? (k ^ 0x80000000u) : ~k;
    return __uint_as_float(u);
}

__global__ __launch_bounds__(1024)
void conv3d_min_part(
    const float* __restrict__ x,     // [16,3,64,64,64]
    const float* __restrict__ wgt,   // [16,3,3,3,3]
    unsigned* __restrict__ outk)     // [16,16,62,62] encoded-min keys
{
    const int tid = threadIdx.x;
    // wave id == output channel; readfirstlane forces wave-uniform -> SGPR
    const int wv  = __builtin_amdgcn_readfirstlane(tid >> 6);
    const int l   = tid & 63;
    const int r0  = l >> 3;           // output row within tile (0..7)
    const int cg  = l & 7;            // col group (0..7)
    const int wc  = cg * 4;           // tile col of px0 (16B-aligned reads)
    const int z   = blockIdx.z;       // 0..31
    const int n   = z >> 1;
    const int dh  = z & 1;            // depth half
    const int base = dh * 28;         // x d-slices [base, base+35]
    const int lo  = dh * 30;          // produced d' range [lo, lo+31]
    const int hi  = lo + 31;
    const int h0  = blockIdx.y * 8;   // 8 h-tiles cover rows 0..63 (62 valid)
    const int w0  = blockIdx.x * 32;  // 2 w-tiles cover cols 0..63 (62 valid)

    // staged x, double-buffered: [3 ci][CH dd][10 rows][36 cols] = 4320 f
    // = 1080 float4 slots (slot F <-> float index 4F, lane-linear for DMA).
    __shared__ __align__(16) float sx[2][4320];

    // ---- hoisted staging address math (chunk 0 of this half) ----
    // slot F -> (ci, dd, rw, g):  F = ((ci*4+dd)*10 + rw)*9 + g
    int goff[2];  // global BYTE offsets; k=1 used only by tid<56
#pragma unroll
    for (int k = 0; k < 2; ++k) {
        int F = tid + 1024 * k;
        if (F > 1079) F = 1079;          // unused lanes: harmless dup
        int ci  = F / 360;               // 360 = 4*10*9
        int rem = F - ci * 360;
        int dd  = rem / 90;              // 90 = 10*9
        int rr  = rem - dd * 90;
        int rw  = rr / 9;
        int g   = rr - rw * 9;
        int gh  = h0 + rw;  if (gh > 63) gh = 63;   // clamp: halo, unused
        int gw  = w0 + g * 4; if (gw > 60) gw = 60; // clamp: cols>=62 unused
        goff[k] = (((ci * 64 + base + dd) * 64 + gh) * 64 + gw) * 4;
    }
    const char* xb = (const char*)(x + (size_t)n * 3 * 64 * 64 * 64);

    // accumulator bank: Aacc[j][px], j = d' - (base + c*4 - 2). j=0,1
    // carry partials from previous chunk; j=4,5 carry out. Static idx only.
    float Aacc[6][4];
#pragma unroll
    for (int j = 0; j < 6; ++j)
#pragma unroll
        for (int p = 0; p < 4; ++p) Aacc[j][p] = 0.f;
    float mv[4] = {1e30f, 1e30f, 1e30f, 1e30f};

    // ---- issue chunk 0 DMA (buffer 0) ----
    {
        char* lb = (char*)&sx[0][0];
        __builtin_amdgcn_global_load_lds(
            (const void*)(xb + goff[0]), (void*)(lb + tid * 16), 16, 0, 0);
        if (tid < 56)
            __builtin_amdgcn_global_load_lds(
                (const void*)(xb + goff[1]),
                (void*)(lb + (1024 + tid) * 16), 16, 0, 0);
    }

    for (int c = 0; c < 9; ++c) {     // 9 chunks x CH=4 = 36 d-slices
        // Drains vmcnt(0): chunk c's DMA landed; other buffer now free.
        __syncthreads();

        // ---- issue chunk c+1 DMA; flies during this chunk's compute ----
        if (c < 8) {
            const char* xc = xb + (size_t)(c + 1) * (CH * 64 * 64 * 4);
            char* lb = (char*)&sx[(c + 1) & 1][0];
            __builtin_amdgcn_global_load_lds(
                (const void*)(xc + goff[0]), (void*)(lb + tid * 16),
                16, 0, 0);
            if (tid < 56)
                __builtin_amdgcn_global_load_lds(
                    (const void*)(xc + goff[1]),
                    (void*)(lb + (1024 + tid) * 16), 16, 0, 0);
        }

        const float* S = sx[c & 1];

        // ---- compute: ci ROLLED so only 27 weights live (SGPR-resident)
#pragma unroll 1
        for (int ci = 0; ci < 3; ++ci) {
            float wsc[27];  // wave-uniform -> s_load -> SGPRs
            {
                const float* wp_ = wgt + (wv * 3 + ci) * 27;
#pragma unroll
                for (int i = 0; i < 27; ++i) wsc[i] = wp_[i];
            }
            const float* Sci = S + ci * (CH * 10 * 36) + r0 * 36 + wc;
#pragma unroll
            for (int dd = 0; dd < CH; ++dd) {
#pragma unroll
                for (int kh = 0; kh < 3; ++kh) {
                    const float4 a = *(const float4*)&Sci[(dd * 10 + kh) * 36];
                    const float2 b =
                        *(const float2*)&Sci[(dd * 10 + kh) * 36 + 4];
                    const float row[6] = {a.x, a.y, a.z, a.w, b.x, b.y};
#pragma unroll
                    for (int kw = 0; kw < 3; ++kw) {
                        const float wk0 = wsc[0  + kh * 3 + kw];  // kd=0
                        const float wk1 = wsc[9  + kh * 3 + kw];  // kd=1
                        const float wk2 = wsc[18 + kh * 3 + kw];  // kd=2
#pragma unroll
                        for (int p = 0; p < 4; ++p) {
                            const float xv = row[kw + p];
                            // x[d] feeds d' = d - kd  ->  j = dd + 2 - kd
                            Aacc[dd + 2][p] = fmaf(xv, wk0, Aacc[dd + 2][p]);
                            Aacc[dd + 1][p] = fmaf(xv, wk1, Aacc[dd + 1][p]);
                            Aacc[dd + 0][p] = fmaf(xv, wk2, Aacc[dd + 0][p]);
                        }
                    }
                }
            }
        }

        // ---- min over completed outputs in this half's d' range ----
        const int dpb = base + c * 4 - 2;  // d' of j=0 (uniform scalar)
#pragma unroll
        for (int j = 0; j < 4; ++j) {
            if (dpb + j >= lo && dpb + j <= hi) {
#pragma unroll
                for (int p = 0; p < 4; ++p)
                    mv[p] = fminf(mv[p], Aacc[j][p]);
            }
        }
        // ---- carry j=4,5 -> j=0,1; zero the rest ----
#pragma unroll
        for (int p = 0; p < 4; ++p) {
            Aacc[0][p] = Aacc[4][p];
            Aacc[1][p] = Aacc[5][p];
        }
#pragma unroll
        for (int j = 2; j < 6; ++j)
#pragma unroll
            for (int p = 0; p < 4; ++p) Aacc[j][p] = 0.f;
    }

    // ---- epilogue: merge partial min via encoded atomicMin ----
    const int hp = h0 + r0;
#pragma unroll
    for (int pp = 0; pp < 4; ++pp) {
        const int wp = w0 + wc + pp;
        if (hp < 62 && wp < 62)
            atomicMin(&outk[(((size_t)n * 16 + wv) * 62 + hp) * 62 + wp],
                      enc_min(mv[pp]));
    }
}

__global__ __launch_bounds__(256)
void softmax_fin(
    unsigned* __restrict__ outk,     // in: encoded min keys; out: fp32
    const float* __restrict__ bias)  // [16]
{
    const int tid = threadIdx.x;
    const int c   = tid & 15;                      // channel = lane
    const int pxi = blockIdx.x * 16 + (tid >> 4);  // 0..61503
    const int n   = pxi / 3844;                    // 3844 = 62*62
    const int rem = pxi - n * 3844;
    const int hp  = rem / 62;
    const int wp  = rem - hp * 62;

    const size_t idx = (((size_t)n * 16 + c) * 62 + hp) * 62 + wp;
    float v = dec_min(outk[idx]) + bias[c];

    float mx = v;
#pragma unroll
    for (int off = 1; off < 16; off <<= 1)
        mx = fmaxf(mx, __shfl_xor(mx, off, 64));
    float e = __expf(v - mx);
    float sum = e;
#pragma unroll
    for (int off = 1; off < 16; off <<= 1)
        sum += __shfl_xor(sum, off, 64);

    ((float*)outk)[idx] = e / sum;
}

extern "C" void kernel_launch(void* const* d_in, const int* in_sizes, int n_in,
                              void* d_out, int out_size, void* d_ws, size_t ws_size,
                              hipStream_t stream) {
    const float* x    = (const float*)d_in[0];
    const float* wgt  = (const float*)d_in[1];
    const float* bias = (const float*)d_in[2];

    // out doubles as the min-merge buffer: 0xFF bytes = max encoded key.
    // out_size is the ELEMENT count (harness reads np.float32[(out_size,)]);
    // memset takes BYTES. R17's nan was this unit bug (3/4 un-initialized).
    hipMemsetAsync(d_out, 0xFF, (size_t)out_size * sizeof(float), stream);

    dim3 g1(2, 8, 32);   // (w-tiles, h-tiles, n*2 depth-halves): 512 blocks
    hipLaunchKernelGGL(conv3d_min_part, g1, dim3(1024), 0, stream,
                       x, wgt, (unsigned*)d_out);

    dim3 g2(3844);       // 61504 px / 16 px-per-block
    hipLaunchKernelGGL(softmax_fin, g2, dim3(256), 0, stream,
                       (unsigned*)d_out, bias);
}

// Round 16
// 198.847 us; speedup vs baseline: 1.4349x; 1.4349x over previous
//
#include <hip/hip_runtime.h>
#include <math.h>

// Fused Conv3d(3->16, k=3, valid) + bias + min over D + softmax over C.
// N=16, CIN=3, COUT=16, K=3, D=H=W=64 -> out [16,16,62,62] fp32.
//
// R19: 2 channels/wave + 2 px/thread — halve the LDS redundancy.
// R18's lesson: the kernel is LDS-PIPE-bound, not latency-bound (D-split
// to 2 blocks/CU changed nothing; per-CU LDS ~150us incl. 98us of bank
// conflicts vs 75us VALU). Root cause: wave-per-channel makes all 16
// waves read the identical x-tile (16x redundancy, conflict-prone b128
// pattern). Fix: wave = (channel-pair, row-half); each 16B read (2xb64)
// feeds 36 FMAs (3kw x 2px x 3kd x 2ch) — same FMA/instr, 2/3 the LDS
// bytes, R11's low-conflict narrow pattern, 8x redundancy.
// Per-CU pipes: LDS ~66us (incl. conflicts) < VALU ~79us -> VALU-bound.
// VGPR: acc 24 + mv 4 + misc ~26 = ~54 fits the immovable 64-bin of
// 1024-thr blocks. SGPR: 54 weights + ~30 = ~85 <= 102 (tripwire).
// Everything else from R16: CH=4, double-buffered global_load_lds,
// rolled-ci SGPR weights, stride-17 sm exchange, single kernel.
// Tripwires: VGPR<=64 no-spill (WRITE ~4.6MB); SGPR<=100; conflicts
// should drop 6.0e7 -> ~2e7; dur 120-155us else theory wrong.

#define CH 4  // d-slices per staged chunk

__global__ __launch_bounds__(1024)
void conv3d_min_softmax(
    const float* __restrict__ x,     // [16,3,64,64,64]
    const float* __restrict__ wgt,   // [16,3,3,3,3]
    const float* __restrict__ bias,  // [16]
    float* __restrict__ out)         // [16,16,62,62]
{
    const int tid = threadIdx.x;
    // wave -> (channel pair, row half); readfirstlane -> SGPR-uniform
    const int wv   = __builtin_amdgcn_readfirstlane(tid >> 6);  // 0..15
    const int half = wv & 1;          // row half of the 8-row tile
    const int co0  = (wv >> 1) * 2;   // first channel of the pair
    const int co1  = co0 + 1;
    const int l    = tid & 63;
    const int r0   = half * 4 + (l >> 4);  // output row in tile (0..7)
    const int cg   = l & 15;               // col-pair group (0..15)
    const int wc   = cg * 2;               // tile col of px0
    const int n    = blockIdx.z;
    const int h0   = blockIdx.y * 8;  // 8 h-tiles cover rows 0..63 (62 valid)
    const int w0   = blockIdx.x * 32; // 2 w-tiles cover cols 0..63 (62 valid)

    // staged x, double-buffered: [3 ci][CH dd][10 rows][36 cols] = 4320 f
    // = 1080 float4 slots (slot F <-> float index 4F, lane-linear for DMA).
    __shared__ __align__(16) float sx[2][4320];
    // softmax exchange: [256 px][17] (stride 17 -> conflict-free reads)
    __shared__ float sm[256 * 17];

    // ---- hoisted staging address math (chunk 0) ----
    // slot F -> (ci, dd, rw, g):  F = ((ci*4+dd)*10 + rw)*9 + g
    int goff[2];  // global BYTE offsets; k=1 used only by tid<56
#pragma unroll
    for (int k = 0; k < 2; ++k) {
        int F = tid + 1024 * k;
        if (F > 1079) F = 1079;          // unused lanes: harmless dup
        int ci  = F / 360;               // 360 = 4*10*9
        int rem = F - ci * 360;
        int dd  = rem / 90;              // 90 = 10*9
        int rr  = rem - dd * 90;
        int rw  = rr / 9;
        int g   = rr - rw * 9;
        int gh  = h0 + rw;  if (gh > 63) gh = 63;   // clamp: halo, unused
        int gw  = w0 + g * 4; if (gw > 60) gw = 60; // clamp: cols>=62 unused
        goff[k] = (((ci * 64 + dd) * 64 + gh) * 64 + gw) * 4;
    }
    const char* xb = (const char*)(x + (size_t)n * 3 * 64 * 64 * 64);

    // accumulator banks per channel: A?acc[j][px], j = d' - (c*4 - 2).
    // j=0,1 carry from previous chunk; j=4,5 carry out. Static idx only.
    float A0acc[6][2], A1acc[6][2];
#pragma unroll
    for (int j = 0; j < 6; ++j)
#pragma unroll
        for (int p = 0; p < 2; ++p) { A0acc[j][p] = 0.f; A1acc[j][p] = 0.f; }
    float mv0[2] = {1e30f, 1e30f};
    float mv1[2] = {1e30f, 1e30f};

    // ---- issue chunk 0 DMA (buffer 0) ----
    {
        char* lb = (char*)&sx[0][0];
        __builtin_amdgcn_global_load_lds(
            (const void*)(xb + goff[0]), (void*)(lb + tid * 16), 16, 0, 0);
        if (tid < 56)
            __builtin_amdgcn_global_load_lds(
                (const void*)(xb + goff[1]),
                (void*)(lb + (1024 + tid) * 16), 16, 0, 0);
    }

    for (int c = 0; c < 16; ++c) {    // 16 chunks x CH=4 = 64 d-slices
        // Drains vmcnt(0): chunk c's DMA landed; other buffer now free.
        __syncthreads();

        // ---- issue chunk c+1 DMA; flies during this chunk's compute ----
        if (c < 15) {
            const char* xc = xb + (size_t)(c + 1) * (CH * 64 * 64 * 4);
            char* lb = (char*)&sx[(c + 1) & 1][0];
            __builtin_amdgcn_global_load_lds(
                (const void*)(xc + goff[0]), (void*)(lb + tid * 16),
                16, 0, 0);
            if (tid < 56)
                __builtin_amdgcn_global_load_lds(
                    (const void*)(xc + goff[1]),
                    (void*)(lb + (1024 + tid) * 16), 16, 0, 0);
        }

        const float* S = sx[c & 1];

        // ---- compute: ci ROLLED; 54 weights (2 ch) live in SGPRs ----
#pragma unroll 1
        for (int ci = 0; ci < 3; ++ci) {
            float ws0[27], ws1[27];  // wave-uniform -> s_load -> SGPRs
            {
                const float* wp0 = wgt + (co0 * 3 + ci) * 27;
                const float* wp1 = wgt + (co1 * 3 + ci) * 27;
#pragma unroll
                for (int i = 0; i < 27; ++i) { ws0[i] = wp0[i]; ws1[i] = wp1[i]; }
            }
            const float* Sci = S + ci * (CH * 10 * 36) + r0 * 36 + wc;
#pragma unroll
            for (int dd = 0; dd < CH; ++dd) {
#pragma unroll
                for (int kh = 0; kh < 3; ++kh) {
                    const float2 a = *(const float2*)&Sci[(dd * 10 + kh) * 36];
                    const float2 b =
                        *(const float2*)&Sci[(dd * 10 + kh) * 36 + 2];
                    const float row[4] = {a.x, a.y, b.x, b.y};
#pragma unroll
                    for (int kw = 0; kw < 3; ++kw) {
                        const float w00 = ws0[0  + kh * 3 + kw];  // ch0 kd=0
                        const float w01 = ws0[9  + kh * 3 + kw];  // ch0 kd=1
                        const float w02 = ws0[18 + kh * 3 + kw];  // ch0 kd=2
                        const float w10 = ws1[0  + kh * 3 + kw];  // ch1 kd=0
                        const float w11 = ws1[9  + kh * 3 + kw];
                        const float w12 = ws1[18 + kh * 3 + kw];
#pragma unroll
                        for (int p = 0; p < 2; ++p) {
                            const float xv = row[kw + p];
                            // x[d] feeds d' = d - kd  ->  j = dd + 2 - kd
                            A0acc[dd + 2][p] = fmaf(xv, w00, A0acc[dd + 2][p]);
                            A0acc[dd + 1][p] = fmaf(xv, w01, A0acc[dd + 1][p]);
                            A0acc[dd + 0][p] = fmaf(xv, w02, A0acc[dd + 0][p]);
                            A1acc[dd + 2][p] = fmaf(xv, w10, A1acc[dd + 2][p]);
                            A1acc[dd + 1][p] = fmaf(xv, w11, A1acc[dd + 1][p]);
                            A1acc[dd + 0][p] = fmaf(xv, w12, A1acc[dd + 0][p]);
                        }
                    }
                }
            }
        }

        // ---- min over completed outputs: j=0..3 <-> d' = c*4-2 .. c*4+1
        const bool full = (c > 0);  // c=0: j=0,1 are d'=-2,-1 (invalid)
#pragma unroll
        for (int j = 0; j < 4; ++j) {
            if (j >= 2 || full) {
#pragma unroll
                for (int p = 0; p < 2; ++p) {
                    mv0[p] = fminf(mv0[p], A0acc[j][p]);
                    mv1[p] = fminf(mv1[p], A1acc[j][p]);
                }
            }
        }
        // ---- carry j=4,5 -> j=0,1; zero the rest ----
#pragma unroll
        for (int p = 0; p < 2; ++p) {
            A0acc[0][p] = A0acc[4][p]; A0acc[1][p] = A0acc[5][p];
            A1acc[0][p] = A1acc[4][p]; A1acc[1][p] = A1acc[5][p];
        }
#pragma unroll
        for (int j = 2; j < 6; ++j)
#pragma unroll
            for (int p = 0; p < 2; ++p) { A0acc[j][p] = 0.f; A1acc[j][p] = 0.f; }
    }

    // ---- epilogue: exchange via LDS, softmax over 16 channels ----
    const float bv0 = bias[co0];
    const float bv1 = bias[co1];
    const int px0 = r0 * 32 + wc;
#pragma unroll
    for (int pp = 0; pp < 2; ++pp) {
        sm[(px0 + pp) * 17 + co0] = mv0[pp] + bv0;
        sm[(px0 + pp) * 17 + co1] = mv1[pp] + bv1;
    }
    __syncthreads();

    const int hp = h0 + r0;
#pragma unroll
    for (int pp = 0; pp < 2; ++pp) {
        const int px = px0 + pp;
        float mx = -1e30f;
#pragma unroll
        for (int j = 0; j < 16; ++j) mx = fmaxf(mx, sm[px * 17 + j]);
        float sum = 0.f;
#pragma unroll
        for (int j = 0; j < 16; ++j) sum += __expf(sm[px * 17 + j] - mx);
        const int wp = w0 + wc + pp;
        if (hp < 62 && wp < 62) {
            const float e0 = __expf(sm[px * 17 + co0] - mx);
            const float e1 = __expf(sm[px * 17 + co1] - mx);
            out[(((size_t)n * 16 + co0) * 62 + hp) * 62 + wp] = e0 / sum;
            out[(((size_t)n * 16 + co1) * 62 + hp) * 62 + wp] = e1 / sum;
        }
    }
}

extern "C" void kernel_launch(void* const* d_in, const int* in_sizes, int n_in,
                              void* d_out, int out_size, void* d_ws, size_t ws_size,
                              hipStream_t stream) {
    const float* x    = (const float*)d_in[0];
    const float* wgt  = (const float*)d_in[1];
    const float* bias = (const float*)d_in[2];
    float* out        = (float*)d_out;
    dim3 grid(2, 8, 16);   // (w-tiles, h-tiles, n)
    dim3 block(1024);      // 16 waves: (channel-pair, row-half)
    hipLaunchKernelGGL(conv3d_min_softmax, grid, block, 0, stream,
                       x, wgt, bias, out);
}